// Round 7
// baseline (285.300 us; speedup 1.0000x reference)
//
#include <hip/hip_runtime.h>

#define BB 8
#define TT 2048
#define CC 1024
#define HH 64
#define MM (BB * TT)   // 16384 rows

typedef _Float16 half8 __attribute__((ext_vector_type(8)));
typedef _Float16 half4 __attribute__((ext_vector_type(4)));
typedef float floatx4 __attribute__((ext_vector_type(4)));

// 16-lane all-reduce max via DPP row-rotate butterfly (VALU pipe, no LDS).
template <int CTRL>
__device__ __forceinline__ float dpp_max_step(float x)
{
    union { float f; int i; } u, v;
    u.f = x;
    v.i = __builtin_amdgcn_update_dpp(u.i, u.i, CTRL, 0xf, 0xf, false);
    return fmaxf(x, v.f);
}
__device__ __forceinline__ float rowmax16(float x)
{
    x = dpp_max_step<0x128>(x);   // ROW_ROR:8
    x = dpp_max_step<0x124>(x);   // ROW_ROR:4
    x = dpp_max_step<0x122>(x);   // ROW_ROR:2
    x = dpp_max_step<0x121>(x);   // ROW_ROR:1
    return x;
}

// async global->LDS, 16B per lane; LDS dest is wave-uniform base + lane*16.
__device__ __forceinline__ void gll16(const float* g, float* l)
{
    __builtin_amdgcn_global_load_lds(
        (const __attribute__((address_space(1))) unsigned int*)g,
        (__attribute__((address_space(3))) unsigned int*)l, 16, 0, 0);
}

#define MEMFENCE asm volatile("" ::: "memory")

// ---------------------------------------------------------------------------
// DIAGNOSTIC 2: effective-shader-clock probe, THROUGHPUT form (no free
// latency parameter). 1 block x 1024 threads = 16 waves on ONE CU = 4
// waves/SIMD. Each thread: 32768 INDEPENDENT v_fmac_f32 (8 rotating
// accumulators -> dep distance 16 issue-cycles >> any VALU latency).
// SIMD-32 executing wave64 VALU = 2 cy/instr is the physical pipe width;
// with 4 resident waves the issue pipe is saturated. Per SIMD:
// 4 waves x 32768 instr x 2 cy = 262144 cycles BY CONSTRUCTION.
//   dur ~110 us -> clock ~2.4 GHz (latency/queueing model; go concurrency)
//   dur ~175 us -> ~1.5 GHz       (mixed)
//   dur ~260 us -> ~1.0 GHz (issue/L1-throughput model; go instr reduction)
// ---------------------------------------------------------------------------
__global__ __launch_bounds__(1024)
void clockprobe2(float* __restrict__ sink)
{
    float a0 = 1.0f + (float)threadIdx.x * 1.0e-9f;
    float a1 = a0 + 1.0e-9f, a2 = a0 + 2.0e-9f, a3 = a0 + 3.0e-9f;
    float a4 = a0 + 4.0e-9f, a5 = a0 + 5.0e-9f, a6 = a0 + 6.0e-9f, a7 = a0 + 7.0e-9f;
    const float b = 1.0000001f;
    const float c = 1.0e-9f;
    for (int i = 0; i < 512; ++i) {      // 512 x 64 = 32768 FMAs
        #pragma unroll
        for (int u = 0; u < 8; ++u) {
            asm volatile("v_fmac_f32 %0, %1, %2" : "+v"(a0) : "v"(b), "v"(c));
            asm volatile("v_fmac_f32 %0, %1, %2" : "+v"(a1) : "v"(b), "v"(c));
            asm volatile("v_fmac_f32 %0, %1, %2" : "+v"(a2) : "v"(b), "v"(c));
            asm volatile("v_fmac_f32 %0, %1, %2" : "+v"(a3) : "v"(b), "v"(c));
            asm volatile("v_fmac_f32 %0, %1, %2" : "+v"(a4) : "v"(b), "v"(c));
            asm volatile("v_fmac_f32 %0, %1, %2" : "+v"(a5) : "v"(b), "v"(c));
            asm volatile("v_fmac_f32 %0, %1, %2" : "+v"(a6) : "v"(b), "v"(c));
            asm volatile("v_fmac_f32 %0, %1, %2" : "+v"(a7) : "v"(b), "v"(c));
        }
    }
    if (threadIdx.x == 0)
        sink[0] = a0 + a1 + a2 + a3 + a4 + a5 + a6 + a7;  // ml[0], overwritten by attn7
}

// ---------------------------------------------------------------------------
// Kernel 0: pack W into chunk-major fp16 layout:
//   Wp[(c*192 + row)*32 + kk] = Wscaled[row][c*32 + kk]   (c = K-chunk of 32)
// rows 0..63 = Wq*8 (sqrt(H) fold), 64..127 = Wk, 128..191 = Wv.
// A 16x16x32 B-fragment (16 rows x k32) is contiguous 1 KB.
// ---------------------------------------------------------------------------
__global__ __launch_bounds__(256)
void w_pack(const float* __restrict__ Wk, const float* __restrict__ Wq,
            const float* __restrict__ Wv, _Float16* __restrict__ Wp)
{
    const int idx = (blockIdx.x * 256 + threadIdx.x) * 8;  // 0..196600
    const int c   = idx / 6144;          // 192*32 = 6144
    const int rm  = idx - c * 6144;
    const int row = rm >> 5;             // 0..191
    const int kk  = rm & 31;             // 0,8,16,24
    const int which = row >> 6;
    const float* __restrict__ src = (which == 0) ? Wq : ((which == 1) ? Wk : Wv);
    const float scale = (which == 0) ? 8.0f : 1.0f;
    const int srow = row & 63;
    const int k = c * 32 + kk;
    const float4 a = *reinterpret_cast<const float4*>(&src[srow * 1024 + k]);
    const float4 b = *reinterpret_cast<const float4*>(&src[srow * 1024 + k + 4]);
    const half8 o = { (_Float16)(a.x * scale), (_Float16)(a.y * scale),
                      (_Float16)(a.z * scale), (_Float16)(a.w * scale),
                      (_Float16)(b.x * scale), (_Float16)(b.y * scale),
                      (_Float16)(b.z * scale), (_Float16)(b.w * scale) };
    *reinterpret_cast<half8*>(&Wp[idx]) = o;
}

// ---------------------------------------------------------------------------
// Kernel 1: QKV projection, v10 (best harness-proven config, 43.9 us).
// LDS-staged block GEMM + per-block K-skew. 256 blocks x 8 waves, 4-deep
// LDS ring, gll dist-3, W reg-dbuf dist-1, counted vmcnt(8) + raw s_barrier.
// ---------------------------------------------------------------------------
__global__ __launch_bounds__(512, 2)
void qkv10(const float* __restrict__ x, const _Float16* __restrict__ Wp,
           _Float16* __restrict__ q16, _Float16* __restrict__ Kp,
           _Float16* __restrict__ Vp)
{
    __shared__ float xs[4][64][32];      // 32 KB ring, NO padding (gll linear)

    const int tid  = threadIdx.x;
    const int lane = tid & 63;
    const int w    = tid >> 6;           // 0..7
    const int blk  = blockIdx.x;         // 0..255
    const int skew = blk & 31;           // per-block K-phase
    const int m_base = blk * 64;
    const int fm = lane & 15;
    const int fq = lane >> 4;
    const int fk = fq * 8;
    const int fr = fq * 4;
    const int wm = w >> 2;               // row half: 0,1
    const int wn = w & 3;                // col group: 0..3

    // staging: wave w stages rows w*8..w*8+7; lane l -> row w*8+(l>>3),
    // physical 16B slot (l&7) receives logical slot (l&7)^(l>>3).
    const float* gsrc = &x[(size_t)(m_base + w * 8 + (lane >> 3)) * CC
                           + ((lane & 7) ^ (lane >> 3)) * 4];
    float* ldst = &xs[0][w * 8][0];      // + buf*2048 floats

    const _Float16* wb = &Wp[(wn * 48 + fm) * 32 + fk];

    floatx4 acc[2][3];
    #pragma unroll
    for (int a = 0; a < 2; ++a)
        #pragma unroll
        for (int n = 0; n < 3; ++n)
            #pragma unroll
            for (int r = 0; r < 4; ++r) acc[a][n][r] = 0.0f;

    half8 wA[3], wB[3];

    // ---- prologue: W(p(0)) -> wA; gll p(0),p(1),p(2) -> slots 0,1,2 ----
    #pragma unroll
    for (int n = 0; n < 3; ++n)
        wA[n] = *reinterpret_cast<const half8*>(wb + (size_t)skew * 6144 + n * 512);
    MEMFENCE;
    gll16(gsrc + (size_t)((skew + 0) & 31) * 32, ldst + 0 * 2048);
    gll16(gsrc + (size_t)((skew + 1) & 31) * 32, ldst + 1 * 2048);
    gll16(gsrc + (size_t)((skew + 2) & 31) * 32, ldst + 2 * 2048);
    asm volatile("s_waitcnt vmcnt(2)" ::: "memory");   // gll(p0)+W(p0) done
    __builtin_amdgcn_s_barrier();
    MEMFENCE;

    // One iter i: [issue W(p(i+1))] [issue gll(p(i+3))] [compute p(i)]
    //             [vmcnt(N)] [bar]
#define QKV_ITER(c, WUSE, WLOAD, DO_W, DO_X, NWAIT)                            \
    {                                                                          \
        if (DO_W) {                                                            \
            const int pw = ((c) + 1 + skew) & 31;                              \
            _Pragma("unroll")                                                  \
            for (int n = 0; n < 3; ++n)                                        \
                WLOAD[n] = *reinterpret_cast<const half8*>(                    \
                    wb + (size_t)pw * 6144 + n * 512);                         \
        }                                                                      \
        MEMFENCE;                                                              \
        if (DO_X) {                                                            \
            const int px = ((c) + 3 + skew) & 31;                              \
            gll16(gsrc + (size_t)px * 32, ldst + (((c) + 3) & 3) * 2048);      \
        }                                                                      \
        _Pragma("unroll")                                                      \
        for (int a = 0; a < 2; ++a) {                                          \
            const int rr = wm * 32 + a * 16 + fm;                              \
            const float* rowp = &xs[(c) & 3][rr][0];                           \
            const int sw = fm & 7;                                             \
            const float4 v0 = *reinterpret_cast<const float4*>(                \
                rowp + ((fq * 2 + 0) ^ sw) * 4);                               \
            const float4 v1 = *reinterpret_cast<const float4*>(                \
                rowp + ((fq * 2 + 1) ^ sw) * 4);                               \
            const half8 af = { (_Float16)v0.x, (_Float16)v0.y,                 \
                               (_Float16)v0.z, (_Float16)v0.w,                 \
                               (_Float16)v1.x, (_Float16)v1.y,                 \
                               (_Float16)v1.z, (_Float16)v1.w };               \
            _Pragma("unroll")                                                  \
            for (int n = 0; n < 3; ++n)                                        \
                acc[a][n] = __builtin_amdgcn_mfma_f32_16x16x32_f16(            \
                    af, WUSE[n], acc[a][n], 0, 0, 0);                          \
        }                                                                      \
        asm volatile("s_waitcnt vmcnt(" #NWAIT ")" ::: "memory");              \
        __builtin_amdgcn_s_barrier();                                          \
        MEMFENCE;                                                              \
    }

    for (int cc = 0; cc < 28; cc += 2) {
        QKV_ITER(cc,     wA, wB, true,  true,  8);
        QKV_ITER(cc + 1, wB, wA, true,  true,  8);
    }
    QKV_ITER(28, wA, wB, true,  true,  8);   // issues W(29), gll(31)
    QKV_ITER(29, wB, wA, true,  false, 4);   // issues W(30); gll(30) done
    QKV_ITER(30, wA, wB, true,  false, 0);   // issues W(31); gll(31) done
    QKV_ITER(31, wB, wA, false, false, 0);   // pure compute
#undef QKV_ITER

    // ---- epilogue: col = wn*48 + n*16 + fm, 16-row tile mt ----
    #pragma unroll
    for (int a = 0; a < 2; ++a) {
        const int mt = blk * 4 + wm * 2 + a;
        #pragma unroll
        for (int n = 0; n < 3; ++n) {
            const int col = wn * 48 + n * 16 + fm;
            if (col < 64) {                          // q: row-major
                #pragma unroll
                for (int r = 0; r < 4; ++r)
                    q16[(size_t)(mt * 16 + fr + r) * HH + col] = (_Float16)acc[a][n][r];
            } else if (col < 128) {                  // k: fragment-packed
                const int h = col - 64;
                _Float16* kp = &Kp[(size_t)(mt * 2 + (h >> 5)) * 512 + (h & 31)];
                #pragma unroll
                for (int r = 0; r < 4; ++r)
                    kp[(fr + r) * 32] = (_Float16)acc[a][n][r];
            } else {                                 // v: fragment-packed (transposed)
                const int h = col - 128;
                const half4 pk = { (_Float16)acc[a][n][0], (_Float16)acc[a][n][1],
                                   (_Float16)acc[a][n][2], (_Float16)acc[a][n][3] };
                *reinterpret_cast<half4*>(
                    &Vp[(size_t)((mt >> 2) * 4 + (h >> 4)) * 1024 +
                        ((mt >> 1) & 1) * 512 + fm * 32 + (mt & 1) * 16 + fr]) = pk;
            }
        }
    }
}

// ---------------------------------------------------------------------------
// Kernel 2: barrier-free split-K causal attention. 3072 single-wave blocks =
// 128 q-tiles(16 rows) x 8 batches x 3 key-segments, longest-first.
// 12 waves/CU (3/SIMD). K/V B-frags: contiguous 1 KB loads from Kp/Vp
// (L2-hot). P via 2.2 KB wave-private LDS (lgkmcnt ordering only).
// DPP row-max + ones-MFMA row-sum. Partials: seg0 -> out (fp32), segs 1,2 ->
// fp16 Op; (m,l) -> ml.
// ---------------------------------------------------------------------------
__global__ __launch_bounds__(64, 4)
void attn7(const _Float16* __restrict__ q16, const _Float16* __restrict__ Kp,
           const _Float16* __restrict__ Vp, float* __restrict__ out,
           _Float16* __restrict__ Op, float* __restrict__ ml)
{
    __shared__ _Float16 Ps[16 * 68];

    const int bid = blockIdx.x;           // 0..3071
    const int it  = 127 - bid / 24;       // longest q-tiles first
    const int sub = bid - (127 - it) * 24;
    const int b   = sub & 7;
    const int s   = sub >> 3;             // segment 0..2

    const int lane = threadIdx.x;
    const int fm = lane & 15;
    const int fq = lane >> 4;
    const int fk = fq * 8;
    const int fr = fq * 4;

    const int Ji = (it >> 2) + 1;
    const int qq = Ji / 3, rem = Ji - qq * 3;
    const int cnt   = qq + (s < rem ? 1 : 0);
    const int start = s * qq + (s < rem ? s : rem);

    const _Float16* __restrict__ kpb = Kp + (size_t)b * TT * HH;
    const _Float16* __restrict__ vpb = Vp + (size_t)b * TT * HH;

    const int qrow = (b * 128 + it) * 16 + fm;
    const half8 qf0 = *reinterpret_cast<const half8*>(&q16[(size_t)qrow * HH + fk]);
    const half8 qf1 = *reinterpret_cast<const half8*>(&q16[(size_t)qrow * HH + 32 + fk]);

    floatx4 O[4], lacc;
    float m_r[4];
    #pragma unroll
    for (int r = 0; r < 4; ++r) {
        m_r[r] = -3.0e38f;
        lacc[r] = 0.0f;
        #pragma unroll
        for (int ht = 0; ht < 4; ++ht) O[ht][r] = 0.0f;
    }
    const half8 ones = { (_Float16)1.f, (_Float16)1.f, (_Float16)1.f, (_Float16)1.f,
                         (_Float16)1.f, (_Float16)1.f, (_Float16)1.f, (_Float16)1.f };

    const int loff = fm * 32 + fk;        // per-lane offset inside a packed frag

    for (int js = 0; js < cnt; ++js) {
        const int jj = start + js;

        // ---- S = Q K^T : 8 MFMAs, B-frags = contiguous 1KB packed loads ----
        floatx4 sa[4];
        #pragma unroll
        for (int nt = 0; nt < 4; ++nt) {
            #pragma unroll
            for (int r = 0; r < 4; ++r) sa[nt][r] = 0.0f;
            const _Float16* kp = &kpb[(size_t)(jj * 4 + nt) * 1024];
            const half8 b0 = *reinterpret_cast<const half8*>(kp + loff);
            const half8 b1 = *reinterpret_cast<const half8*>(kp + 512 + loff);
            sa[nt] = __builtin_amdgcn_mfma_f32_16x16x32_f16(qf0, b0, sa[nt], 0, 0, 0);
            sa[nt] = __builtin_amdgcn_mfma_f32_16x16x32_f16(qf1, b1, sa[nt], 0, 0, 0);
        }

        // ---- causal mask (only the diagonal tile) ----
        if (jj == (it >> 2)) {
            const int rbase = it * 16 + fr;
            #pragma unroll
            for (int nt = 0; nt < 4; ++nt) {
                const int col = jj * 64 + nt * 16 + fm;
                #pragma unroll
                for (int r = 0; r < 4; ++r)
                    if (col > rbase + r) sa[nt][r] = -3.0e38f;
            }
        }

        // ---- online softmax: DPP row-max; row-sum via ones-MFMA ----
        #pragma unroll
        for (int r = 0; r < 4; ++r) {
            float mx = fmaxf(fmaxf(sa[0][r], sa[1][r]), fmaxf(sa[2][r], sa[3][r]));
            mx = rowmax16(mx);
            const float mn = fmaxf(m_r[r], mx);
            const float alpha = __expf(m_r[r] - mn);
            m_r[r] = mn;
            _Float16* pp = &Ps[(fr + r) * 68 + fm];
            pp[0]  = (_Float16)__expf(sa[0][r] - mn);
            pp[16] = (_Float16)__expf(sa[1][r] - mn);
            pp[32] = (_Float16)__expf(sa[2][r] - mn);
            pp[48] = (_Float16)__expf(sa[3][r] - mn);
            lacc[r] *= alpha;
            O[0][r] *= alpha; O[1][r] *= alpha; O[2][r] *= alpha; O[3][r] *= alpha;
        }
        // wave-private LDS: lgkmcnt ordering suffices, no barrier

        // ---- O += P V, l += P 1 : 10 MFMAs ----
        #pragma unroll
        for (int ch = 0; ch < 2; ++ch) {
            const half8 pa = *reinterpret_cast<const half8*>(&Ps[fm * 68 + ch * 32 + fk]);
            lacc = __builtin_amdgcn_mfma_f32_16x16x32_f16(pa, ones, lacc, 0, 0, 0);
            #pragma unroll
            for (int ht = 0; ht < 4; ++ht) {
                const half8 vb = *reinterpret_cast<const half8*>(
                    &vpb[(size_t)(jj * 4 + ht) * 1024 + ch * 512 + loff]);
                O[ht] = __builtin_amdgcn_mfma_f32_16x16x32_f16(pa, vb, O[ht], 0, 0, 0);
            }
        }
    }

    // ---- epilogue: write segment partial (unnormalized O, m, l) ----
    #pragma unroll
    for (int r = 0; r < 4; ++r) {
        const int grow = (b * 128 + it) * 16 + fr + r;
        if (s == 0) {
            #pragma unroll
            for (int ht = 0; ht < 4; ++ht)
                out[(size_t)grow * HH + ht * 16 + fm] = O[ht][r];
        } else {
            #pragma unroll
            for (int ht = 0; ht < 4; ++ht)
                Op[((size_t)(s - 1) * MM + grow) * HH + ht * 16 + fm] = (_Float16)O[ht][r];
        }
        if (fm == 0) {
            ml[((size_t)s * MM + grow) * 2 + 0] = m_r[r];
            ml[((size_t)s * MM + grow) * 2 + 1] = lacc[r];
        }
    }
}

// ---------------------------------------------------------------------------
// Kernel 3: flash-decode combine of the 3 segment partials.
// ---------------------------------------------------------------------------
__global__ __launch_bounds__(256)
void combine(float* __restrict__ out, const _Float16* __restrict__ Op,
             const float* __restrict__ ml)
{
    const int tid  = threadIdx.x;
    const int grow = blockIdx.x * 64 + (tid >> 2);
    const int c0   = (tid & 3) * 16;

    const float m0 = ml[(size_t)grow * 2 + 0];
    const float l0 = ml[(size_t)grow * 2 + 1];
    const float m1 = ml[((size_t)MM + grow) * 2 + 0];
    const float l1 = ml[((size_t)MM + grow) * 2 + 1];
    const float m2 = ml[((size_t)2 * MM + grow) * 2 + 0];
    const float l2 = ml[((size_t)2 * MM + grow) * 2 + 1];

    const float M  = fmaxf(m0, fmaxf(m1, m2));
    const float w0 = __expf(m0 - M);
    const float w1 = __expf(m1 - M);
    const float w2 = __expf(m2 - M);
    const float inv = 1.0f / (w0 * l0 + w1 * l1 + w2 * l2);

    #pragma unroll
    for (int i = 0; i < 16; i += 4) {
        float4 o0 = *reinterpret_cast<float4*>(&out[(size_t)grow * HH + c0 + i]);
        const half4 h1 = *reinterpret_cast<const half4*>(&Op[(size_t)grow * HH + c0 + i]);
        const half4 h2 = *reinterpret_cast<const half4*>(&Op[(size_t)MM * HH + (size_t)grow * HH + c0 + i]);
        o0.x = (w0 * o0.x + w1 * (float)h1[0] + w2 * (float)h2[0]) * inv;
        o0.y = (w0 * o0.y + w1 * (float)h1[1] + w2 * (float)h2[1]) * inv;
        o0.z = (w0 * o0.z + w1 * (float)h1[2] + w2 * (float)h2[2]) * inv;
        o0.w = (w0 * o0.w + w1 * (float)h1[3] + w2 * (float)h2[3]) * inv;
        *reinterpret_cast<float4*>(&out[(size_t)grow * HH + c0 + i]) = o0;
    }
}

// ---------------------------------------------------------------------------
extern "C" void kernel_launch(void* const* d_in, const int* in_sizes, int n_in,
                              void* d_out, int out_size, void* d_ws, size_t ws_size,
                              hipStream_t stream)
{
    (void)in_sizes; (void)n_in; (void)out_size; (void)ws_size;

    const float* x  = (const float*)d_in[0];
    const float* Wk = (const float*)d_in[1];
    const float* Wq = (const float*)d_in[2];
    const float* Wv = (const float*)d_in[3];
    float* out = (float*)d_out;

    _Float16* base = (_Float16*)d_ws;
    _Float16* q16 = base;                                  // MM*HH halves
    _Float16* Kp  = base + (size_t)MM * HH;                // MM*HH
    _Float16* Vp  = base + (size_t)2 * MM * HH;            // MM*HH
    _Float16* Wp  = base + (size_t)3 * MM * HH;            // 192*1024
    _Float16* Op  = Wp + 192 * 1024;                       // 2*MM*HH
    float*    ml  = (float*)(Op + (size_t)2 * MM * HH);    // 3*MM*2 floats

    clockprobe2<<<dim3(1), dim3(1024), 0, stream>>>(ml);   // diagnostic; ml overwritten by attn7
    w_pack<<<dim3(96), dim3(256), 0, stream>>>(Wk, Wq, Wv, Wp);
    qkv10<<<dim3(256), dim3(512), 0, stream>>>(x, Wp, q16, Kp, Vp);
    attn7<<<dim3(3072), dim3(64), 0, stream>>>(q16, Kp, Vp, out, Op, ml);
    combine<<<dim3(256), dim3(256), 0, stream>>>(out, Op, ml);
}

// Round 9
// 150.924 us; speedup vs baseline: 1.8904x; 1.8904x over previous
//
#include <hip/hip_runtime.h>

#define BB 8
#define TT 2048
#define CC 1024
#define HH 64
#define MM (BB * TT)   // 16384 rows

typedef _Float16 half8 __attribute__((ext_vector_type(8)));
typedef _Float16 half4 __attribute__((ext_vector_type(4)));
typedef float floatx4 __attribute__((ext_vector_type(4)));

// 16-lane all-reduce max via DPP row-rotate butterfly (VALU pipe, no LDS).
template <int CTRL>
__device__ __forceinline__ float dpp_max_step(float x)
{
    union { float f; int i; } u, v;
    u.f = x;
    v.i = __builtin_amdgcn_update_dpp(u.i, u.i, CTRL, 0xf, 0xf, false);
    return fmaxf(x, v.f);
}
__device__ __forceinline__ float rowmax16(float x)
{
    x = dpp_max_step<0x128>(x);   // ROW_ROR:8
    x = dpp_max_step<0x124>(x);   // ROW_ROR:4
    x = dpp_max_step<0x122>(x);   // ROW_ROR:2
    x = dpp_max_step<0x121>(x);   // ROW_ROR:1
    return x;
}

// async global->LDS, 16B per lane; LDS dest is wave-uniform base + lane*16.
__device__ __forceinline__ void gll16(const float* g, float* l)
{
    __builtin_amdgcn_global_load_lds(
        (const __attribute__((address_space(1))) unsigned int*)g,
        (__attribute__((address_space(3))) unsigned int*)l, 16, 0, 0);
}
__device__ __forceinline__ void gll16h(const _Float16* g, _Float16* l)
{
    __builtin_amdgcn_global_load_lds(
        (const __attribute__((address_space(1))) unsigned int*)g,
        (__attribute__((address_space(3))) unsigned int*)l, 16, 0, 0);
}

#define MEMFENCE asm volatile("" ::: "memory")

// ---------------------------------------------------------------------------
// Kernel 0: pack W into LANE-MAJOR fragment layout (v12):
//   fragment (c, nf): 16 cols x k32-chunk, stored 1 KB contiguous in MFMA
//   lane order: Wp[((c*12 + nf)*64 + l)*8 .. +7] =
//       Wscaled[col = nf*16 + (l&15)][k = c*32 + (l>>4)*8 .. +7]
// cols 0..63 = Wq*8 (sqrt(H) fold), 64..127 = Wk, 128..191 = Wv.
// Lane-major => LDS consume is lane*16B consecutive (conflict-free b128).
// ---------------------------------------------------------------------------
__global__ __launch_bounds__(256)
void w_pack(const float* __restrict__ Wk, const float* __restrict__ Wq,
            const float* __restrict__ Wv, _Float16* __restrict__ Wp)
{
    const int T   = blockIdx.x * 256 + threadIdx.x;   // 0..24575
    const int c   = T / 768;           // k-chunk 0..31
    const int rem = T - c * 768;
    const int nf  = rem >> 6;          // col fragment 0..11
    const int l   = rem & 63;          // lane within fragment
    const int col = nf * 16 + (l & 15);
    const int k   = c * 32 + (l >> 4) * 8;
    const int which = col >> 6;
    const float* __restrict__ src = (which == 0) ? Wq : ((which == 1) ? Wk : Wv);
    const float scale = (which == 0) ? 8.0f : 1.0f;
    const int srow = col & 63;
    const float4 a = *reinterpret_cast<const float4*>(&src[srow * 1024 + k]);
    const float4 b = *reinterpret_cast<const float4*>(&src[srow * 1024 + k + 4]);
    const half8 o = { (_Float16)(a.x * scale), (_Float16)(a.y * scale),
                      (_Float16)(a.z * scale), (_Float16)(a.w * scale),
                      (_Float16)(b.x * scale), (_Float16)(b.y * scale),
                      (_Float16)(b.z * scale), (_Float16)(b.w * scale) };
    *reinterpret_cast<half8*>(&Wp[(size_t)T * 8]) = o;
}

// ---------------------------------------------------------------------------
// Kernel 1: QKV projection, v12 — VMEM-traffic reduction (the measured
// limiter: ~86 cy per 1KB wave-load ~= 12 B/cy/CU ~= 6.1 TB/s device L1
// ceiling; clock probe R7 = 2.0 GHz so the cycle budget is real).
// v10 moved 32 KB/chunk/CU (24 KB W duplicated across wn-pairs + 8 KB x).
// v12 routes W through LDS ONCE: 12 KB/chunk via global_load_lds into a
// ring-3 LDS buffer; waves consume via conflict-free lane-major ds_read_b128
// (Wp re-layout). Per-chunk VMEM: 20 instr / 20 KB (8 x-gll + 12 W-gll).
// Staging distance 2 on both (ring-3), asymmetric counted vmcnt
// (waves 0-3: 2 W-glls -> N=3; waves 4-7: 1 W-gll -> N=2), raw s_barrier.
// 256 blocks x 8 waves; per-block K-skew kept.
// ---------------------------------------------------------------------------
__global__ __launch_bounds__(512, 1)
void qkv12(const float* __restrict__ x, const _Float16* __restrict__ Wp,
           _Float16* __restrict__ q16, _Float16* __restrict__ Kp,
           _Float16* __restrict__ Vp)
{
    __shared__ float    xs[3][64][32];   // 24 KB x ring (linear, gll dest)
    __shared__ _Float16 Ws[3][6144];     // 36 KB W ring (lane-major frags)

    const int tid  = threadIdx.x;
    const int lane = tid & 63;
    const int w    = tid >> 6;           // 0..7
    const int blk  = blockIdx.x;         // 0..255
    const int skew = blk & 31;           // per-block K-phase
    const int m_base = blk * 64;
    const int fm = lane & 15;
    const int fq = lane >> 4;
    const int fk = fq * 8;
    const int fr = fq * 4;
    const int wm = w >> 2;               // row half: 0,1
    const int wn = w & 3;                // col group: 0..3

    // x staging: wave w stages rows w*8..w*8+7; lane l -> row w*8+(l>>3),
    // physical 16B slot (l&7) receives logical slot (l&7)^(l>>3).
    const float* gsrc = &x[(size_t)(m_base + w * 8 + (lane >> 3)) * CC
                           + ((lane & 7) ^ (lane >> 3)) * 4];
    float* xbase = &xs[0][w * 8][0];     // + slot*2048 floats

    // W staging: 12 glls of 1 KB per chunk; waves 0-3 take 2, waves 4-7 take 1
    const _Float16* wsrc = Wp + lane * 8;

    floatx4 acc[2][3];
    #pragma unroll
    for (int a = 0; a < 2; ++a)
        #pragma unroll
        for (int n = 0; n < 3; ++n)
            #pragma unroll
            for (int r = 0; r < 4; ++r) acc[a][n][r] = 0.0f;

#define STAGE_X(p, slot) gll16(gsrc + (size_t)(p) * 32, xbase + (slot) * 2048)
#define STAGE_W(p, slot) do {                                                  \
        const _Float16* wsp = wsrc + (size_t)(p) * 6144;                       \
        if (w < 4) {                                                           \
            gll16h(wsp + (2 * w) * 512,     &Ws[slot][(2 * w) * 512]);         \
            gll16h(wsp + (2 * w + 1) * 512, &Ws[slot][(2 * w + 1) * 512]);     \
        } else {                                                               \
            gll16h(wsp + (4 + w) * 512,     &Ws[slot][(4 + w) * 512]);         \
        }                                                                      \
    } while (0)

#define COMPUTE(sc) do {                                                       \
        const half8 wf0 = *reinterpret_cast<const half8*>(                     \
            &Ws[sc][(wn * 3 + 0) * 512 + lane * 8]);                           \
        const half8 wf1 = *reinterpret_cast<const half8*>(                     \
            &Ws[sc][(wn * 3 + 1) * 512 + lane * 8]);                           \
        const half8 wf2 = *reinterpret_cast<const half8*>(                     \
            &Ws[sc][(wn * 3 + 2) * 512 + lane * 8]);                           \
        _Pragma("unroll")                                                      \
        for (int a = 0; a < 2; ++a) {                                          \
            const float* rowp = &xs[sc][wm * 32 + a * 16 + fm][0];             \
            const int sw = fm & 7;                                             \
            const float4 v0 = *reinterpret_cast<const float4*>(                \
                rowp + ((fq * 2 + 0) ^ sw) * 4);                               \
            const float4 v1 = *reinterpret_cast<const float4*>(                \
                rowp + ((fq * 2 + 1) ^ sw) * 4);                               \
            const half8 af = { (_Float16)v0.x, (_Float16)v0.y,                 \
                               (_Float16)v0.z, (_Float16)v0.w,                 \
                               (_Float16)v1.x, (_Float16)v1.y,                 \
                               (_Float16)v1.z, (_Float16)v1.w };               \
            acc[a][0] = __builtin_amdgcn_mfma_f32_16x16x32_f16(af, wf0, acc[a][0], 0, 0, 0); \
            acc[a][1] = __builtin_amdgcn_mfma_f32_16x16x32_f16(af, wf1, acc[a][1], 0, 0, 0); \
            acc[a][2] = __builtin_amdgcn_mfma_f32_16x16x32_f16(af, wf2, acc[a][2], 0, 0, 0); \
        }                                                                      \
    } while (0)

#define WAITB(NLO, NHI) do {                                                   \
        if (w < 4) asm volatile("s_waitcnt vmcnt(" #NLO ")" ::: "memory");     \
        else       asm volatile("s_waitcnt vmcnt(" #NHI ")" ::: "memory");     \
        __builtin_amdgcn_s_barrier();                                          \
        MEMFENCE;                                                              \
    } while (0)

    // ---- prologue: stage chunks 0,1 into slots 0,1 ----
    MEMFENCE;
    STAGE_W(skew, 0);               STAGE_X(skew, 0);
    STAGE_W((skew + 1) & 31, 1);    STAGE_X((skew + 1) & 31, 1);
    WAITB(3, 2);                    // force chunk 0; allow chunk 1 in flight

    // ---- main loop: stage c+2 (dist-2, ring-3), compute c, counted wait ----
    for (int c = 0; c < 30; ++c) {
        const int pp = (c + 2 + skew) & 31;
        const int sl = (c + 2) % 3;
        STAGE_W(pp, sl);
        STAGE_X(pp, sl);
        MEMFENCE;
        COMPUTE(c % 3);
        WAITB(3, 2);                // force chunk c+1's stages
    }
    COMPUTE(0);                     // c = 30 (30%3 == 0)
    WAITB(0, 0);                    // force chunk 31's stages
    COMPUTE(1);                     // c = 31 (31%3 == 1)

#undef STAGE_X
#undef STAGE_W
#undef COMPUTE
#undef WAITB

    // ---- epilogue: col = wn*48 + n*16 + fm, 16-row tile mt ----
    #pragma unroll
    for (int a = 0; a < 2; ++a) {
        const int mt = blk * 4 + wm * 2 + a;
        #pragma unroll
        for (int n = 0; n < 3; ++n) {
            const int col = wn * 48 + n * 16 + fm;
            if (col < 64) {                          // q: row-major
                #pragma unroll
                for (int r = 0; r < 4; ++r)
                    q16[(size_t)(mt * 16 + fr + r) * HH + col] = (_Float16)acc[a][n][r];
            } else if (col < 128) {                  // k: fragment-packed
                const int h = col - 64;
                _Float16* kp = &Kp[(size_t)(mt * 2 + (h >> 5)) * 512 + (h & 31)];
                #pragma unroll
                for (int r = 0; r < 4; ++r)
                    kp[(fr + r) * 32] = (_Float16)acc[a][n][r];
            } else {                                 // v: fragment-packed (transposed)
                const int h = col - 128;
                const half4 pk = { (_Float16)acc[a][n][0], (_Float16)acc[a][n][1],
                                   (_Float16)acc[a][n][2], (_Float16)acc[a][n][3] };
                *reinterpret_cast<half4*>(
                    &Vp[(size_t)((mt >> 2) * 4 + (h >> 4)) * 1024 +
                        ((mt >> 1) & 1) * 512 + fm * 32 + (mt & 1) * 16 + fr]) = pk;
            }
        }
    }
}

// ---------------------------------------------------------------------------
// Kernel 2: barrier-free split-K causal attention. 3072 single-wave blocks =
// 128 q-tiles(16 rows) x 8 batches x 3 key-segments, longest-first.
// 12 waves/CU (3/SIMD). K/V B-frags: contiguous 1 KB loads from Kp/Vp
// (L2-hot). P via 2.2 KB wave-private LDS (lgkmcnt ordering only).
// DPP row-max + ones-MFMA row-sum. Partials: seg0 -> out (fp32), segs 1,2 ->
// fp16 Op; (m,l) -> ml.
// ---------------------------------------------------------------------------
__global__ __launch_bounds__(64, 4)
void attn7(const _Float16* __restrict__ q16, const _Float16* __restrict__ Kp,
           const _Float16* __restrict__ Vp, float* __restrict__ out,
           _Float16* __restrict__ Op, float* __restrict__ ml)
{
    __shared__ _Float16 Ps[16 * 68];

    const int bid = blockIdx.x;           // 0..3071
    const int it  = 127 - bid / 24;       // longest q-tiles first
    const int sub = bid - (127 - it) * 24;
    const int b   = sub & 7;
    const int s   = sub >> 3;             // segment 0..2

    const int lane = threadIdx.x;
    const int fm = lane & 15;
    const int fq = lane >> 4;
    const int fk = fq * 8;
    const int fr = fq * 4;

    const int Ji = (it >> 2) + 1;
    const int qq = Ji / 3, rem = Ji - qq * 3;
    const int cnt   = qq + (s < rem ? 1 : 0);
    const int start = s * qq + (s < rem ? s : rem);

    const _Float16* __restrict__ kpb = Kp + (size_t)b * TT * HH;
    const _Float16* __restrict__ vpb = Vp + (size_t)b * TT * HH;

    const int qrow = (b * 128 + it) * 16 + fm;
    const half8 qf0 = *reinterpret_cast<const half8*>(&q16[(size_t)qrow * HH + fk]);
    const half8 qf1 = *reinterpret_cast<const half8*>(&q16[(size_t)qrow * HH + 32 + fk]);

    floatx4 O[4], lacc;
    float m_r[4];
    #pragma unroll
    for (int r = 0; r < 4; ++r) {
        m_r[r] = -3.0e38f;
        lacc[r] = 0.0f;
        #pragma unroll
        for (int ht = 0; ht < 4; ++ht) O[ht][r] = 0.0f;
    }
    const half8 ones = { (_Float16)1.f, (_Float16)1.f, (_Float16)1.f, (_Float16)1.f,
                         (_Float16)1.f, (_Float16)1.f, (_Float16)1.f, (_Float16)1.f };

    const int loff = fm * 32 + fk;        // per-lane offset inside a packed frag

    for (int js = 0; js < cnt; ++js) {
        const int jj = start + js;

        // ---- S = Q K^T : 8 MFMAs, B-frags = contiguous 1KB packed loads ----
        floatx4 sa[4];
        #pragma unroll
        for (int nt = 0; nt < 4; ++nt) {
            #pragma unroll
            for (int r = 0; r < 4; ++r) sa[nt][r] = 0.0f;
            const _Float16* kp = &kpb[(size_t)(jj * 4 + nt) * 1024];
            const half8 b0 = *reinterpret_cast<const half8*>(kp + loff);
            const half8 b1 = *reinterpret_cast<const half8*>(kp + 512 + loff);
            sa[nt] = __builtin_amdgcn_mfma_f32_16x16x32_f16(qf0, b0, sa[nt], 0, 0, 0);
            sa[nt] = __builtin_amdgcn_mfma_f32_16x16x32_f16(qf1, b1, sa[nt], 0, 0, 0);
        }

        // ---- causal mask (only the diagonal tile) ----
        if (jj == (it >> 2)) {
            const int rbase = it * 16 + fr;
            #pragma unroll
            for (int nt = 0; nt < 4; ++nt) {
                const int col = jj * 64 + nt * 16 + fm;
                #pragma unroll
                for (int r = 0; r < 4; ++r)
                    if (col > rbase + r) sa[nt][r] = -3.0e38f;
            }
        }

        // ---- online softmax: DPP row-max; row-sum via ones-MFMA ----
        #pragma unroll
        for (int r = 0; r < 4; ++r) {
            float mx = fmaxf(fmaxf(sa[0][r], sa[1][r]), fmaxf(sa[2][r], sa[3][r]));
            mx = rowmax16(mx);
            const float mn = fmaxf(m_r[r], mx);
            const float alpha = __expf(m_r[r] - mn);
            m_r[r] = mn;
            _Float16* pp = &Ps[(fr + r) * 68 + fm];
            pp[0]  = (_Float16)__expf(sa[0][r] - mn);
            pp[16] = (_Float16)__expf(sa[1][r] - mn);
            pp[32] = (_Float16)__expf(sa[2][r] - mn);
            pp[48] = (_Float16)__expf(sa[3][r] - mn);
            lacc[r] *= alpha;
            O[0][r] *= alpha; O[1][r] *= alpha; O[2][r] *= alpha; O[3][r] *= alpha;
        }
        // wave-private LDS: lgkmcnt ordering suffices, no barrier

        // ---- O += P V, l += P 1 : 10 MFMAs ----
        #pragma unroll
        for (int ch = 0; ch < 2; ++ch) {
            const half8 pa = *reinterpret_cast<const half8*>(&Ps[fm * 68 + ch * 32 + fk]);
            lacc = __builtin_amdgcn_mfma_f32_16x16x32_f16(pa, ones, lacc, 0, 0, 0);
            #pragma unroll
            for (int ht = 0; ht < 4; ++ht) {
                const half8 vb = *reinterpret_cast<const half8*>(
                    &vpb[(size_t)(jj * 4 + ht) * 1024 + ch * 512 + loff]);
                O[ht] = __builtin_amdgcn_mfma_f32_16x16x32_f16(pa, vb, O[ht], 0, 0, 0);
            }
        }
    }

    // ---- epilogue: write segment partial (unnormalized O, m, l) ----
    #pragma unroll
    for (int r = 0; r < 4; ++r) {
        const int grow = (b * 128 + it) * 16 + fr + r;
        if (s == 0) {
            #pragma unroll
            for (int ht = 0; ht < 4; ++ht)
                out[(size_t)grow * HH + ht * 16 + fm] = O[ht][r];
        } else {
            #pragma unroll
            for (int ht = 0; ht < 4; ++ht)
                Op[((size_t)(s - 1) * MM + grow) * HH + ht * 16 + fm] = (_Float16)O[ht][r];
        }
        if (fm == 0) {
            ml[((size_t)s * MM + grow) * 2 + 0] = m_r[r];
            ml[((size_t)s * MM + grow) * 2 + 1] = lacc[r];
        }
    }
}

// ---------------------------------------------------------------------------
// Kernel 3: flash-decode combine of the 3 segment partials.
// ---------------------------------------------------------------------------
__global__ __launch_bounds__(256)
void combine(float* __restrict__ out, const _Float16* __restrict__ Op,
             const float* __restrict__ ml)
{
    const int tid  = threadIdx.x;
    const int grow = blockIdx.x * 64 + (tid >> 2);
    const int c0   = (tid & 3) * 16;

    const float m0 = ml[(size_t)grow * 2 + 0];
    const float l0 = ml[(size_t)grow * 2 + 1];
    const float m1 = ml[((size_t)MM + grow) * 2 + 0];
    const float l1 = ml[((size_t)MM + grow) * 2 + 1];
    const float m2 = ml[((size_t)2 * MM + grow) * 2 + 0];
    const float l2 = ml[((size_t)2 * MM + grow) * 2 + 1];

    const float M  = fmaxf(m0, fmaxf(m1, m2));
    const float w0 = __expf(m0 - M);
    const float w1 = __expf(m1 - M);
    const float w2 = __expf(m2 - M);
    const float inv = 1.0f / (w0 * l0 + w1 * l1 + w2 * l2);

    #pragma unroll
    for (int i = 0; i < 16; i += 4) {
        float4 o0 = *reinterpret_cast<float4*>(&out[(size_t)grow * HH + c0 + i]);
        const half4 h1 = *reinterpret_cast<const half4*>(&Op[(size_t)grow * HH + c0 + i]);
        const half4 h2 = *reinterpret_cast<const half4*>(&Op[(size_t)MM * HH + (size_t)grow * HH + c0 + i]);
        o0.x = (w0 * o0.x + w1 * (float)h1[0] + w2 * (float)h2[0]) * inv;
        o0.y = (w0 * o0.y + w1 * (float)h1[1] + w2 * (float)h2[1]) * inv;
        o0.z = (w0 * o0.z + w1 * (float)h1[2] + w2 * (float)h2[2]) * inv;
        o0.w = (w0 * o0.w + w1 * (float)h1[3] + w2 * (float)h2[3]) * inv;
        *reinterpret_cast<float4*>(&out[(size_t)grow * HH + c0 + i]) = o0;
    }
}

// ---------------------------------------------------------------------------
extern "C" void kernel_launch(void* const* d_in, const int* in_sizes, int n_in,
                              void* d_out, int out_size, void* d_ws, size_t ws_size,
                              hipStream_t stream)
{
    (void)in_sizes; (void)n_in; (void)out_size; (void)ws_size;

    const float* x  = (const float*)d_in[0];
    const float* Wk = (const float*)d_in[1];
    const float* Wq = (const float*)d_in[2];
    const float* Wv = (const float*)d_in[3];
    float* out = (float*)d_out;

    _Float16* base = (_Float16*)d_ws;
    _Float16* q16 = base;                                  // MM*HH halves
    _Float16* Kp  = base + (size_t)MM * HH;                // MM*HH
    _Float16* Vp  = base + (size_t)2 * MM * HH;            // MM*HH
    _Float16* Wp  = base + (size_t)3 * MM * HH;            // 192*1024
    _Float16* Op  = Wp + 192 * 1024;                       // 2*MM*HH
    float*    ml  = (float*)(Op + (size_t)2 * MM * HH);    // 3*MM*2 floats

    w_pack<<<dim3(96), dim3(256), 0, stream>>>(Wk, Wq, Wv, Wp);
    qkv12<<<dim3(256), dim3(512), 0, stream>>>(x, Wp, q16, Kp, Vp);
    attn7<<<dim3(3072), dim3(64), 0, stream>>>(q16, Kp, Vp, out, Op, ml);
    combine<<<dim3(256), dim3(256), 0, stream>>>(out, Op, ml);
}

// Round 10
// 146.896 us; speedup vs baseline: 1.9422x; 1.0274x over previous
//
#include <hip/hip_runtime.h>

#define BB 8
#define TT 2048
#define CC 1024
#define HH 64
#define MM (BB * TT)   // 16384 rows

typedef _Float16 half8 __attribute__((ext_vector_type(8)));
typedef _Float16 half4 __attribute__((ext_vector_type(4)));
typedef float floatx4 __attribute__((ext_vector_type(4)));

// 16-lane all-reduce max via DPP row-rotate butterfly (VALU pipe, no LDS).
template <int CTRL>
__device__ __forceinline__ float dpp_max_step(float x)
{
    union { float f; int i; } u, v;
    u.f = x;
    v.i = __builtin_amdgcn_update_dpp(u.i, u.i, CTRL, 0xf, 0xf, false);
    return fmaxf(x, v.f);
}
__device__ __forceinline__ float rowmax16(float x)
{
    x = dpp_max_step<0x128>(x);   // ROW_ROR:8
    x = dpp_max_step<0x124>(x);   // ROW_ROR:4
    x = dpp_max_step<0x122>(x);   // ROW_ROR:2
    x = dpp_max_step<0x121>(x);   // ROW_ROR:1
    return x;
}

// async global->LDS, 16B per lane; LDS dest is wave-uniform base + lane*16.
__device__ __forceinline__ void gll16(const float* g, float* l)
{
    __builtin_amdgcn_global_load_lds(
        (const __attribute__((address_space(1))) unsigned int*)g,
        (__attribute__((address_space(3))) unsigned int*)l, 16, 0, 0);
}
__device__ __forceinline__ void gll16h(const _Float16* g, _Float16* l)
{
    __builtin_amdgcn_global_load_lds(
        (const __attribute__((address_space(1))) unsigned int*)g,
        (__attribute__((address_space(3))) unsigned int*)l, 16, 0, 0);
}

#define MEMFENCE asm volatile("" ::: "memory")

// ---------------------------------------------------------------------------
// Kernel 0: pack W into LANE-MAJOR fragment layout:
//   fragment (c, nf): 16 cols x k32-chunk, stored 1 KB contiguous in MFMA
//   lane order: Wp[((c*12 + nf)*64 + l)*8 .. +7] =
//       Wscaled[col = nf*16 + (l&15)][k = c*32 + (l>>4)*8 .. +7]
// cols 0..63 = Wq*8 (sqrt(H) fold), 64..127 = Wk, 128..191 = Wv.
// ---------------------------------------------------------------------------
__global__ __launch_bounds__(256)
void w_pack(const float* __restrict__ Wk, const float* __restrict__ Wq,
            const float* __restrict__ Wv, _Float16* __restrict__ Wp)
{
    const int T   = blockIdx.x * 256 + threadIdx.x;   // 0..24575
    const int c   = T / 768;           // k-chunk 0..31
    const int rem = T - c * 768;
    const int nf  = rem >> 6;          // col fragment 0..11
    const int l   = rem & 63;          // lane within fragment
    const int col = nf * 16 + (l & 15);
    const int k   = c * 32 + (l >> 4) * 8;
    const int which = col >> 6;
    const float* __restrict__ src = (which == 0) ? Wq : ((which == 1) ? Wk : Wv);
    const float scale = (which == 0) ? 8.0f : 1.0f;
    const int srow = col & 63;
    const float4 a = *reinterpret_cast<const float4*>(&src[srow * 1024 + k]);
    const float4 b = *reinterpret_cast<const float4*>(&src[srow * 1024 + k + 4]);
    const half8 o = { (_Float16)(a.x * scale), (_Float16)(a.y * scale),
                      (_Float16)(a.z * scale), (_Float16)(a.w * scale),
                      (_Float16)(b.x * scale), (_Float16)(b.y * scale),
                      (_Float16)(b.z * scale), (_Float16)(b.w * scale) };
    *reinterpret_cast<half8*>(&Wp[(size_t)T * 8]) = o;
}

// ---------------------------------------------------------------------------
// Kernel 1: QKV projection, v12 (harness-proven, 44.5 us; frozen this round).
// W staged through LDS once per chunk via global_load_lds (lane-major Wp),
// x via source-swizzled gll; ring-3, counted vmcnt, raw s_barrier.
// ---------------------------------------------------------------------------
__global__ __launch_bounds__(512, 1)
void qkv12(const float* __restrict__ x, const _Float16* __restrict__ Wp,
           _Float16* __restrict__ q16, _Float16* __restrict__ Kp,
           _Float16* __restrict__ Vp)
{
    __shared__ float    xs[3][64][32];   // 24 KB x ring (linear, gll dest)
    __shared__ _Float16 Ws[3][6144];     // 36 KB W ring (lane-major frags)

    const int tid  = threadIdx.x;
    const int lane = tid & 63;
    const int w    = tid >> 6;           // 0..7
    const int blk  = blockIdx.x;         // 0..255
    const int skew = blk & 31;           // per-block K-phase
    const int m_base = blk * 64;
    const int fm = lane & 15;
    const int fq = lane >> 4;
    const int fk = fq * 8;
    const int fr = fq * 4;
    const int wm = w >> 2;               // row half: 0,1
    const int wn = w & 3;                // col group: 0..3

    const float* gsrc = &x[(size_t)(m_base + w * 8 + (lane >> 3)) * CC
                           + ((lane & 7) ^ (lane >> 3)) * 4];
    float* xbase = &xs[0][w * 8][0];     // + slot*2048 floats

    const _Float16* wsrc = Wp + lane * 8;

    floatx4 acc[2][3];
    #pragma unroll
    for (int a = 0; a < 2; ++a)
        #pragma unroll
        for (int n = 0; n < 3; ++n)
            #pragma unroll
            for (int r = 0; r < 4; ++r) acc[a][n][r] = 0.0f;

#define STAGE_X(p, slot) gll16(gsrc + (size_t)(p) * 32, xbase + (slot) * 2048)
#define STAGE_W(p, slot) do {                                                  \
        const _Float16* wsp = wsrc + (size_t)(p) * 6144;                       \
        if (w < 4) {                                                           \
            gll16h(wsp + (2 * w) * 512,     &Ws[slot][(2 * w) * 512]);         \
            gll16h(wsp + (2 * w + 1) * 512, &Ws[slot][(2 * w + 1) * 512]);     \
        } else {                                                               \
            gll16h(wsp + (4 + w) * 512,     &Ws[slot][(4 + w) * 512]);         \
        }                                                                      \
    } while (0)

#define COMPUTE(sc) do {                                                       \
        const half8 wf0 = *reinterpret_cast<const half8*>(                     \
            &Ws[sc][(wn * 3 + 0) * 512 + lane * 8]);                           \
        const half8 wf1 = *reinterpret_cast<const half8*>(                     \
            &Ws[sc][(wn * 3 + 1) * 512 + lane * 8]);                           \
        const half8 wf2 = *reinterpret_cast<const half8*>(                     \
            &Ws[sc][(wn * 3 + 2) * 512 + lane * 8]);                           \
        _Pragma("unroll")                                                      \
        for (int a = 0; a < 2; ++a) {                                          \
            const float* rowp = &xs[sc][wm * 32 + a * 16 + fm][0];             \
            const int sw = fm & 7;                                             \
            const float4 v0 = *reinterpret_cast<const float4*>(                \
                rowp + ((fq * 2 + 0) ^ sw) * 4);                               \
            const float4 v1 = *reinterpret_cast<const float4*>(                \
                rowp + ((fq * 2 + 1) ^ sw) * 4);                               \
            const half8 af = { (_Float16)v0.x, (_Float16)v0.y,                 \
                               (_Float16)v0.z, (_Float16)v0.w,                 \
                               (_Float16)v1.x, (_Float16)v1.y,                 \
                               (_Float16)v1.z, (_Float16)v1.w };               \
            acc[a][0] = __builtin_amdgcn_mfma_f32_16x16x32_f16(af, wf0, acc[a][0], 0, 0, 0); \
            acc[a][1] = __builtin_amdgcn_mfma_f32_16x16x32_f16(af, wf1, acc[a][1], 0, 0, 0); \
            acc[a][2] = __builtin_amdgcn_mfma_f32_16x16x32_f16(af, wf2, acc[a][2], 0, 0, 0); \
        }                                                                      \
    } while (0)

#define WAITB(NLO, NHI) do {                                                   \
        if (w < 4) asm volatile("s_waitcnt vmcnt(" #NLO ")" ::: "memory");     \
        else       asm volatile("s_waitcnt vmcnt(" #NHI ")" ::: "memory");     \
        __builtin_amdgcn_s_barrier();                                          \
        MEMFENCE;                                                              \
    } while (0)

    // ---- prologue: stage chunks 0,1 into slots 0,1 ----
    MEMFENCE;
    STAGE_W(skew, 0);               STAGE_X(skew, 0);
    STAGE_W((skew + 1) & 31, 1);    STAGE_X((skew + 1) & 31, 1);
    WAITB(3, 2);                    // force chunk 0; allow chunk 1 in flight

    // ---- main loop: stage c+2 (dist-2, ring-3), compute c, counted wait ----
    for (int c = 0; c < 30; ++c) {
        const int pp = (c + 2 + skew) & 31;
        const int sl = (c + 2) % 3;
        STAGE_W(pp, sl);
        STAGE_X(pp, sl);
        MEMFENCE;
        COMPUTE(c % 3);
        WAITB(3, 2);                // force chunk c+1's stages
    }
    COMPUTE(0);                     // c = 30 (30%3 == 0)
    WAITB(0, 0);                    // force chunk 31's stages
    COMPUTE(1);                     // c = 31 (31%3 == 1)

#undef STAGE_X
#undef STAGE_W
#undef COMPUTE
#undef WAITB

    // ---- epilogue: col = wn*48 + n*16 + fm, 16-row tile mt ----
    #pragma unroll
    for (int a = 0; a < 2; ++a) {
        const int mt = blk * 4 + wm * 2 + a;
        #pragma unroll
        for (int n = 0; n < 3; ++n) {
            const int col = wn * 48 + n * 16 + fm;
            if (col < 64) {                          // q: row-major
                #pragma unroll
                for (int r = 0; r < 4; ++r)
                    q16[(size_t)(mt * 16 + fr + r) * HH + col] = (_Float16)acc[a][n][r];
            } else if (col < 128) {                  // k: fragment-packed
                const int h = col - 64;
                _Float16* kp = &Kp[(size_t)(mt * 2 + (h >> 5)) * 512 + (h & 31)];
                #pragma unroll
                for (int r = 0; r < 4; ++r)
                    kp[(fr + r) * 32] = (_Float16)acc[a][n][r];
            } else {                                 // v: fragment-packed (transposed)
                const int h = col - 128;
                const half4 pk = { (_Float16)acc[a][n][0], (_Float16)acc[a][n][1],
                                   (_Float16)acc[a][n][2], (_Float16)acc[a][n][3] };
                *reinterpret_cast<half4*>(
                    &Vp[(size_t)((mt >> 2) * 4 + (h >> 4)) * 1024 +
                        ((mt >> 1) & 1) * 512 + fm * 32 + (mt & 1) * 16 + fr]) = pk;
            }
        }
    }
}

// ---------------------------------------------------------------------------
// Kernel 2: attn8 — K/V LDS-shared 4-wave blocks.
// attn7 was VMEM-bound: 3072 single-wave blocks x ~5.5 j-steps x 16 KB of
// K/V fragment loads = 270 MB ~= 44 us at the ~6.1 TB/s fabric ceiling, with
// 4 waves of the same tile-group reading the SAME K/V stream independently.
// attn8: the 4 q-tiles sharing g = it>>2 have IDENTICAL jj-ranges and
// segment splits (Ji = g+1), so group them into one 4-wave block (768 blocks
// x 256 thr, 3 blocks/CU = 12 waves/CU as before). Per jj-step the block
// stages 16 KB of K/V to LDS ONCE via 16 global_load_lds (4 per wave),
// double-buffered, vmcnt(0)+barrier per step. gll writes linearly, so the
// GLOBAL source is pre-permuted by s(l) = (l&15)*4 + (l>>4) (the fragment
// lane-offset map) and LDS reads are linear lane*16 B -> 2-way conflict-free.
// Device K/V traffic: 270 -> 67 MB.
// ---------------------------------------------------------------------------
__global__ __launch_bounds__(256, 3)
void attn8(const _Float16* __restrict__ q16, const _Float16* __restrict__ Kp,
           const _Float16* __restrict__ Vp, float* __restrict__ out,
           _Float16* __restrict__ Op, float* __restrict__ ml)
{
    __shared__ _Float16 Kls[2][4][1024];   // 16 KB: [buf][nt][piece*512 + slot]
    __shared__ _Float16 Vls[2][4][1024];   // 16 KB: [buf][ht][ch*512 + slot]
    __shared__ _Float16 Ps[4][16 * 68];    // 8.7 KB, per-wave private

    const int bid = blockIdx.x;           // 0..767
    const int g   = 31 - bid / 24;        // tile-group, longest first
    const int sub = bid - (31 - g) * 24;
    const int b   = sub & 7;
    const int s   = sub >> 3;             // segment 0..2

    const int tid  = threadIdx.x;
    const int lane = tid & 63;
    const int w    = tid >> 6;            // 0..3
    const int it   = g * 4 + w;           // this wave's q-tile
    const int fm = lane & 15;
    const int fq = lane >> 4;
    const int fk = fq * 8;
    const int fr = fq * 4;

    const int Ji = g + 1;                 // == (it>>2)+1, uniform in block
    const int qq = Ji / 3, rem = Ji - qq * 3;
    const int cnt   = qq + (s < rem ? 1 : 0);
    const int start = s * qq + (s < rem ? s : rem);

    const _Float16* __restrict__ kpb = Kp + (size_t)b * TT * HH;
    const _Float16* __restrict__ vpb = Vp + (size_t)b * TT * HH;

    const int qrow = (b * 128 + it) * 16 + fm;
    const half8 qf0 = *reinterpret_cast<const half8*>(&q16[(size_t)qrow * HH + fk]);
    const half8 qf1 = *reinterpret_cast<const half8*>(&q16[(size_t)qrow * HH + 32 + fk]);

    floatx4 O[4], lacc;
    float m_r[4];
    #pragma unroll
    for (int r = 0; r < 4; ++r) {
        m_r[r] = -3.0e38f;
        lacc[r] = 0.0f;
        #pragma unroll
        for (int ht = 0; ht < 4; ++ht) O[ht][r] = 0.0f;
    }
    const half8 ones = { (_Float16)1.f, (_Float16)1.f, (_Float16)1.f, (_Float16)1.f,
                         (_Float16)1.f, (_Float16)1.f, (_Float16)1.f, (_Float16)1.f };

    // stage-source permutation: LDS slot l receives fragment slot s(l)
    const int sperm = ((lane & 15) * 4 + (lane >> 4)) * 8;   // halves

    if (cnt > 0) {
        // ---- prologue: stage jj = start into buf 0 (4 glls per wave) ----
        {
            const _Float16* kgp = &kpb[(size_t)(start * 4 + w) * 1024];
            const _Float16* vgp = &vpb[(size_t)(start * 4 + w) * 1024];
            gll16h(kgp + sperm,       &Kls[0][w][0]);
            gll16h(kgp + 512 + sperm, &Kls[0][w][512]);
            gll16h(vgp + sperm,       &Vls[0][w][0]);
            gll16h(vgp + 512 + sperm, &Vls[0][w][512]);
        }
        asm volatile("s_waitcnt vmcnt(0)" ::: "memory");
        __builtin_amdgcn_s_barrier();
        MEMFENCE;

        int buf = 0;
        for (int js = 0; js < cnt; ++js) {
            const int jj = start + js;

            // ---- stage jj+1 into buf^1 while computing jj ----
            if (js + 1 < cnt) {
                const _Float16* kgp = &kpb[(size_t)((jj + 1) * 4 + w) * 1024];
                const _Float16* vgp = &vpb[(size_t)((jj + 1) * 4 + w) * 1024];
                gll16h(kgp + sperm,       &Kls[buf ^ 1][w][0]);
                gll16h(kgp + 512 + sperm, &Kls[buf ^ 1][w][512]);
                gll16h(vgp + sperm,       &Vls[buf ^ 1][w][0]);
                gll16h(vgp + 512 + sperm, &Vls[buf ^ 1][w][512]);
            }
            MEMFENCE;

            // ---- S = Q K^T : 8 MFMAs, B-frags linear from LDS ----
            floatx4 sa[4];
            #pragma unroll
            for (int nt = 0; nt < 4; ++nt) {
                #pragma unroll
                for (int r = 0; r < 4; ++r) sa[nt][r] = 0.0f;
                const half8 b0 = *reinterpret_cast<const half8*>(&Kls[buf][nt][lane * 8]);
                const half8 b1 = *reinterpret_cast<const half8*>(&Kls[buf][nt][512 + lane * 8]);
                sa[nt] = __builtin_amdgcn_mfma_f32_16x16x32_f16(qf0, b0, sa[nt], 0, 0, 0);
                sa[nt] = __builtin_amdgcn_mfma_f32_16x16x32_f16(qf1, b1, sa[nt], 0, 0, 0);
            }

            // ---- causal mask (diagonal 64-col block; per-wave rows) ----
            if (jj == g) {
                const int rbase = it * 16 + fr;
                #pragma unroll
                for (int nt = 0; nt < 4; ++nt) {
                    const int col = jj * 64 + nt * 16 + fm;
                    #pragma unroll
                    for (int r = 0; r < 4; ++r)
                        if (col > rbase + r) sa[nt][r] = -3.0e38f;
                }
            }

            // ---- online softmax: DPP row-max; row-sum via ones-MFMA ----
            #pragma unroll
            for (int r = 0; r < 4; ++r) {
                float mx = fmaxf(fmaxf(sa[0][r], sa[1][r]), fmaxf(sa[2][r], sa[3][r]));
                mx = rowmax16(mx);
                const float mn = fmaxf(m_r[r], mx);
                const float alpha = __expf(m_r[r] - mn);
                m_r[r] = mn;
                _Float16* pp = &Ps[w][(fr + r) * 68 + fm];
                pp[0]  = (_Float16)__expf(sa[0][r] - mn);
                pp[16] = (_Float16)__expf(sa[1][r] - mn);
                pp[32] = (_Float16)__expf(sa[2][r] - mn);
                pp[48] = (_Float16)__expf(sa[3][r] - mn);
                lacc[r] *= alpha;
                O[0][r] *= alpha; O[1][r] *= alpha; O[2][r] *= alpha; O[3][r] *= alpha;
            }
            // wave-private Ps: lgkmcnt ordering suffices, no barrier

            // ---- O += P V, l += P 1 : 10 MFMAs, V linear from LDS ----
            #pragma unroll
            for (int ch = 0; ch < 2; ++ch) {
                const half8 pa = *reinterpret_cast<const half8*>(&Ps[w][fm * 68 + ch * 32 + fk]);
                lacc = __builtin_amdgcn_mfma_f32_16x16x32_f16(pa, ones, lacc, 0, 0, 0);
                #pragma unroll
                for (int ht = 0; ht < 4; ++ht) {
                    const half8 vb = *reinterpret_cast<const half8*>(
                        &Vls[buf][ht][ch * 512 + lane * 8]);
                    O[ht] = __builtin_amdgcn_mfma_f32_16x16x32_f16(pa, vb, O[ht], 0, 0, 0);
                }
            }

            // ---- step end: own stage-glls drained, then block barrier ----
            asm volatile("s_waitcnt vmcnt(0)" ::: "memory");
            __builtin_amdgcn_s_barrier();
            MEMFENCE;
            buf ^= 1;
        }
    }

    // ---- epilogue: write segment partial (unnormalized O, m, l) ----
    #pragma unroll
    for (int r = 0; r < 4; ++r) {
        const int grow = (b * 128 + it) * 16 + fr + r;
        if (s == 0) {
            #pragma unroll
            for (int ht = 0; ht < 4; ++ht)
                out[(size_t)grow * HH + ht * 16 + fm] = O[ht][r];
        } else {
            #pragma unroll
            for (int ht = 0; ht < 4; ++ht)
                Op[((size_t)(s - 1) * MM + grow) * HH + ht * 16 + fm] = (_Float16)O[ht][r];
        }
        if (fm == 0) {
            ml[((size_t)s * MM + grow) * 2 + 0] = m_r[r];
            ml[((size_t)s * MM + grow) * 2 + 1] = lacc[r];
        }
    }
}

// ---------------------------------------------------------------------------
// Kernel 3: flash-decode combine of the 3 segment partials.
// ---------------------------------------------------------------------------
__global__ __launch_bounds__(256)
void combine(float* __restrict__ out, const _Float16* __restrict__ Op,
             const float* __restrict__ ml)
{
    const int tid  = threadIdx.x;
    const int grow = blockIdx.x * 64 + (tid >> 2);
    const int c0   = (tid & 3) * 16;

    const float m0 = ml[(size_t)grow * 2 + 0];
    const float l0 = ml[(size_t)grow * 2 + 1];
    const float m1 = ml[((size_t)MM + grow) * 2 + 0];
    const float l1 = ml[((size_t)MM + grow) * 2 + 1];
    const float m2 = ml[((size_t)2 * MM + grow) * 2 + 0];
    const float l2 = ml[((size_t)2 * MM + grow) * 2 + 1];

    const float M  = fmaxf(m0, fmaxf(m1, m2));
    const float w0 = __expf(m0 - M);
    const float w1 = __expf(m1 - M);
    const float w2 = __expf(m2 - M);
    const float inv = 1.0f / (w0 * l0 + w1 * l1 + w2 * l2);

    #pragma unroll
    for (int i = 0; i < 16; i += 4) {
        float4 o0 = *reinterpret_cast<float4*>(&out[(size_t)grow * HH + c0 + i]);
        const half4 h1 = *reinterpret_cast<const half4*>(&Op[(size_t)grow * HH + c0 + i]);
        const half4 h2 = *reinterpret_cast<const half4*>(&Op[(size_t)MM * HH + (size_t)grow * HH + c0 + i]);
        o0.x = (w0 * o0.x + w1 * (float)h1[0] + w2 * (float)h2[0]) * inv;
        o0.y = (w0 * o0.y + w1 * (float)h1[1] + w2 * (float)h2[1]) * inv;
        o0.z = (w0 * o0.z + w1 * (float)h1[2] + w2 * (float)h2[2]) * inv;
        o0.w = (w0 * o0.w + w1 * (float)h1[3] + w2 * (float)h2[3]) * inv;
        *reinterpret_cast<float4*>(&out[(size_t)grow * HH + c0 + i]) = o0;
    }
}

// ---------------------------------------------------------------------------
extern "C" void kernel_launch(void* const* d_in, const int* in_sizes, int n_in,
                              void* d_out, int out_size, void* d_ws, size_t ws_size,
                              hipStream_t stream)
{
    (void)in_sizes; (void)n_in; (void)out_size; (void)ws_size;

    const float* x  = (const float*)d_in[0];
    const float* Wk = (const float*)d_in[1];
    const float* Wq = (const float*)d_in[2];
    const float* Wv = (const float*)d_in[3];
    float* out = (float*)d_out;

    _Float16* base = (_Float16*)d_ws;
    _Float16* q16 = base;                                  // MM*HH halves
    _Float16* Kp  = base + (size_t)MM * HH;                // MM*HH
    _Float16* Vp  = base + (size_t)2 * MM * HH;            // MM*HH
    _Float16* Wp  = base + (size_t)3 * MM * HH;            // 192*1024
    _Float16* Op  = Wp + 192 * 1024;                       // 2*MM*HH
    float*    ml  = (float*)(Op + (size_t)2 * MM * HH);    // 3*MM*2 floats

    w_pack<<<dim3(96), dim3(256), 0, stream>>>(Wk, Wq, Wv, Wp);
    qkv12<<<dim3(256), dim3(512), 0, stream>>>(x, Wp, q16, Kp, Vp);
    attn8<<<dim3(768), dim3(256), 0, stream>>>(q16, Kp, Vp, out, Op, ml);
    combine<<<dim3(256), dim3(256), 0, stream>>>(out, Op, ml);
}